// Round 7
// baseline (2461.272 us; speedup 1.0000x reference)
//
#include <hip/hip_runtime.h>
#include <cmath>

#define B_   64
#define T_   256
#define D_   1024
#define DIN_ 1074
#define H_   256

typedef _Float16 h2_t  __attribute__((ext_vector_type(2)));
typedef _Float16 f16x8 __attribute__((ext_vector_type(8)));
typedef float    f32x4 __attribute__((ext_vector_type(4)));

// ---------------------------------------------------------------------------
// PRE[mv][n] = bias_dir[row] + sum_{k<50} mask_embed[mv][k] * W_ih_dir[row][1024+k]
// ---------------------------------------------------------------------------
__global__ __launch_bounds__(256) void k_pre(
    const float* __restrict__ me, const float* __restrict__ Wf,
    const float* __restrict__ Wb, const float* __restrict__ bf,
    const float* __restrict__ bb, float* __restrict__ PRE) {
  int idx = blockIdx.x * 256 + threadIdx.x;   // 4096 total
  if (idx >= 4096) return;
  int mv = idx >> 11, n = idx & 2047;
  int dir = n >> 10, row = n & 1023;
  const float* W    = dir ? Wb : Wf;
  const float* bias = dir ? bb : bf;
  const float* wrow = W + (size_t)row * DIN_ + 1024;
  const float* m    = me + mv * 50;
  float s = bias[row];
  #pragma unroll 10
  for (int k = 0; k < 50; ++k) s += m[k] * wrow[k];
  PRE[idx] = s;
}

// ---------------------------------------------------------------------------
// Pack W_hh (both dirs) to fp16, layout WH[dir][k8][row=gate*256+hc][8 halfs]
// ---------------------------------------------------------------------------
__global__ __launch_bounds__(256) void k_wph(
    const float* __restrict__ Whf, const float* __restrict__ Whb,
    _Float16* __restrict__ WH) {
  int idx = blockIdx.x * 256 + threadIdx.x;   // 65536 total
  int dir = idx >> 15, rem = idx & 32767;
  int k8 = rem >> 10, gate = (rem >> 8) & 3, hc = rem & 255;
  const float* W = dir ? Whb : Whf;
  const float* src = W + (size_t)(gate * 256 + hc) * H_ + k8 * 8;
  _Float16* dst = WH + ((size_t)(((dir * 32 + k8) * 4 + gate) * 256 + hc)) * 8;
  #pragma unroll
  for (int e = 0; e < 8; ++e) dst[e] = (_Float16)src[e];
}

// ---------------------------------------------------------------------------
// Pack sents -> PA fp16 [16384][1024] and W_ih rows (cols 0..1023) -> PB fp16
// ---------------------------------------------------------------------------
__global__ __launch_bounds__(256) void k_pack(
    const float* __restrict__ sents, const float* __restrict__ Wf,
    const float* __restrict__ Wb, _Float16* __restrict__ PA,
    _Float16* __restrict__ PB) {
  int i = blockIdx.x * 256 + threadIdx.x;     // 2359296 total
  if (i < 2097152) {
    size_t off = (size_t)i * 8;
    float4 a = *(const float4*)(sents + off);
    float4 b = *(const float4*)(sents + off + 4);
    _Float16 h[8] = {(_Float16)a.x, (_Float16)a.y, (_Float16)a.z, (_Float16)a.w,
                     (_Float16)b.x, (_Float16)b.y, (_Float16)b.z, (_Float16)b.w};
    *(uint4*)(PA + off) = *(const uint4*)h;
  } else {
    int j = i - 2097152;                      // 262144
    int n = j >> 7, k8 = j & 127;
    const float* src = (n < 1024) ? (Wf + (size_t)n * DIN_ + k8 * 8)
                                  : (Wb + (size_t)(n - 1024) * DIN_ + k8 * 8);
    float2 a0 = *(const float2*)(src);
    float2 a1 = *(const float2*)(src + 2);
    float2 a2 = *(const float2*)(src + 4);
    float2 a3 = *(const float2*)(src + 6);
    _Float16 h[8] = {(_Float16)a0.x, (_Float16)a0.y, (_Float16)a1.x, (_Float16)a1.y,
                     (_Float16)a2.x, (_Float16)a2.y, (_Float16)a3.x, (_Float16)a3.y};
    *(uint4*)(PB + (size_t)n * 1024 + k8 * 8) = *(const uint4*)h;
  }
}

// ---------------------------------------------------------------------------
// XW = PA @ PB^T + PRE[mask] : M=16384, N=2048, K=1024, fp16 MFMA 16x16x32.
// LDS row stride 40 halfs (80B): fragment reads are 2-way bank aliased (free).
// ---------------------------------------------------------------------------
#define LSTR 40
__global__ __launch_bounds__(256) void k_mm(
    const _Float16* __restrict__ PA, const _Float16* __restrict__ PB,
    const float* __restrict__ PRE, const int* __restrict__ masks,
    float* __restrict__ XW) {
  __shared__ __align__(16) _Float16 Al[128 * LSTR];
  __shared__ __align__(16) _Float16 Bl[128 * LSTR];
  int tid = threadIdx.x;
  int lane = tid & 63, wave = tid >> 6;
  int wr = wave >> 1, wc = wave & 1;
  int m0 = blockIdx.y * 128, n0 = blockIdx.x * 128;

  int r0 = tid >> 2;
  int kc = (tid & 3) * 8;
  const _Float16* asrc0 = PA + (size_t)(m0 + r0) * 1024 + kc;
  const _Float16* asrc1 = asrc0 + (size_t)64 * 1024;
  const _Float16* bsrc0 = PB + (size_t)(n0 + r0) * 1024 + kc;
  const _Float16* bsrc1 = bsrc0 + (size_t)64 * 1024;
  _Float16* adst0 = Al + r0 * LSTR + kc;
  _Float16* adst1 = Al + (r0 + 64) * LSTR + kc;
  _Float16* bdst0 = Bl + r0 * LSTR + kc;
  _Float16* bdst1 = Bl + (r0 + 64) * LSTR + kc;

  f32x4 acc[4][4];
  #pragma unroll
  for (int i = 0; i < 4; ++i)
    #pragma unroll
    for (int j = 0; j < 4; ++j)
      acc[i][j] = (f32x4){0.f, 0.f, 0.f, 0.f};

  int fr = lane & 15, fk = (lane >> 4) * 8;
  const _Float16* arow = Al + (wr * 64 + fr) * LSTR + fk;
  const _Float16* brow = Bl + (wc * 64 + fr) * LSTR + fk;

  for (int k0 = 0; k0 < 1024; k0 += 32) {
    uint4 a0 = *(const uint4*)(asrc0 + k0);
    uint4 a1 = *(const uint4*)(asrc1 + k0);
    uint4 b0 = *(const uint4*)(bsrc0 + k0);
    uint4 b1 = *(const uint4*)(bsrc1 + k0);
    __syncthreads();
    *(uint4*)adst0 = a0; *(uint4*)adst1 = a1;
    *(uint4*)bdst0 = b0; *(uint4*)bdst1 = b1;
    __syncthreads();
    f16x8 af[4], bf[4];
    #pragma unroll
    for (int fm = 0; fm < 4; ++fm) af[fm] = *(const f16x8*)(arow + fm * 16 * LSTR);
    #pragma unroll
    for (int fn = 0; fn < 4; ++fn) bf[fn] = *(const f16x8*)(brow + fn * 16 * LSTR);
    #pragma unroll
    for (int fm = 0; fm < 4; ++fm)
      #pragma unroll
      for (int fn = 0; fn < 4; ++fn)
        acc[fm][fn] = __builtin_amdgcn_mfma_f32_16x16x32_f16(af[fm], bf[fn], acc[fm][fn], 0, 0, 0);
  }

  int cr = (lane >> 4) * 4;
  #pragma unroll
  for (int fm = 0; fm < 4; ++fm) {
    #pragma unroll
    for (int r = 0; r < 4; ++r) {
      int m = m0 + wr * 64 + fm * 16 + cr + r;
      int mv = masks[m];
      const float* pr = PRE + mv * 2048;
      float* orow = XW + (size_t)m * 2048;
      #pragma unroll
      for (int fn = 0; fn < 4; ++fn) {
        int n = n0 + wc * 64 + fn * 16 + fr;
        orow[n] = acc[fm][fn][r] + pr[n];
      }
    }
  }
}

// ---------------------------------------------------------------------------
// Batched persistent LSTM v7: 32 WGs = 16 groups(4 batches) x 2 dirs,
// 1024 thr (16 waves, 4/SIMD — the allocator's natural 128-VGPR target).
// Thread owns ONE W row (gate=tid>>8, hc=tid&255) for all 4 batches.
// W split SIZED TO FIT 128 VGPRs (the r4-r6 lesson: demand > target => spill
// to scratch = same bytes as streaming):
//   slices 0..7   LDS-resident (128KB, loaded once)
//   slices 8..15  register-resident (8 x uint4 = 32 VGPRs)
//   slices 16..31 streamed per step in two 8-slice banks (32+32 VGPRs flight)
// Per-step stream = 256KB (~1.7us via L1) overlapped with ~1.7us of fdot2.
// ---------------------------------------------------------------------------
#define NLDS 8
#define NRG  8

// one slice x 4 batches: 16 fdot2. hv reads are wave-uniform broadcasts.
#define DOT1(W, K8)                                                     \
  {                                                                     \
    const unsigned int* wq_ = (const unsigned int*)&(W);                \
    _Pragma("unroll")                                                   \
    for (int q_ = 0; q_ < 4; ++q_) {                                    \
      uint4 hv_ = hp[(K8) * 4 + q_];                                    \
      h2_t w2_ = __builtin_bit_cast(h2_t, wq_[q_]);                     \
      a0 = __builtin_amdgcn_fdot2(w2_, __builtin_bit_cast(h2_t, hv_.x), a0, false); \
      a1 = __builtin_amdgcn_fdot2(w2_, __builtin_bit_cast(h2_t, hv_.y), a1, false); \
      a2 = __builtin_amdgcn_fdot2(w2_, __builtin_bit_cast(h2_t, hv_.z), a2, false); \
      a3 = __builtin_amdgcn_fdot2(w2_, __builtin_bit_cast(h2_t, hv_.w), a3, false); \
    }                                                                   \
  }

__global__ __launch_bounds__(1024) void k_lstm(
    const float* __restrict__ XW, const _Float16* __restrict__ WH,
    const int* __restrict__ lens, float* __restrict__ ctx) {
  int bx = blockIdx.x;
  int dir = bx & 1, grp = bx >> 1;
  int tid = threadIdx.x;
  int hc = tid & 255, hi = tid >> 8;   // hi = gate (compute) / batch j (update)

  __shared__ __align__(16) uint4    Wl[NLDS * 1024];   // 128 KB
  __shared__ __align__(16) _Float16 hsT[1024];         // 2 KB  [k2][j][2]
  __shared__ __align__(16) float    gacc[4 * 1024];    // 16 KB [j][gate][hc]

  int b0 = grp * 4;
  int myb = b0 + hi;
  int mylen = lens[myb];
  int lmax = max(max(lens[b0], lens[b0 + 1]), max(lens[b0 + 2], lens[b0 + 3]));

  const uint4* WHd = (const uint4*)WH + (size_t)dir * 32768;

  // one-time LDS preload of slices 0..7 (coalesced, 8 x 16KB)
  #pragma unroll
  for (int i = 0; i < NLDS; ++i) Wl[i * 1024 + tid] = WHd[i * 1024 + tid];

  // register-resident slices 8..15 (32 VGPRs — fits the 128 budget)
  uint4 wr0 = WHd[(NLDS + 0) * 1024 + tid];
  uint4 wr1 = WHd[(NLDS + 1) * 1024 + tid];
  uint4 wr2 = WHd[(NLDS + 2) * 1024 + tid];
  uint4 wr3 = WHd[(NLDS + 3) * 1024 + tid];
  uint4 wr4 = WHd[(NLDS + 4) * 1024 + tid];
  uint4 wr5 = WHd[(NLDS + 5) * 1024 + tid];
  uint4 wr6 = WHd[(NLDS + 6) * 1024 + tid];
  uint4 wr7 = WHd[(NLDS + 7) * 1024 + tid];

  hsT[tid & 1023] = (_Float16)0.f;
  float cstate = 0.f;

  const uint4* hp = (const uint4*)hsT;
  const float* xwb = XW + (size_t)myb * T_ * 2048 + dir * 1024;
  float* cbase = ctx + (size_t)myb * T_ * 512 + dir * 256;
  __syncthreads();

  for (int s = 0; s < lmax; ++s) {
    // stream bank 1 (slices 16..23): issue first, consume after reg+LDS dots
    uint4 sa0 = WHd[16 * 1024 + tid], sa1 = WHd[17 * 1024 + tid];
    uint4 sa2 = WHd[18 * 1024 + tid], sa3 = WHd[19 * 1024 + tid];
    uint4 sa4 = WHd[20 * 1024 + tid], sa5 = WHd[21 * 1024 + tid];
    uint4 sa6 = WHd[22 * 1024 + tid], sa7 = WHd[23 * 1024 + tid];

    // XW gate prefetch for this thread's update-batch (clamped address)
    int sc = min(s, mylen - 1);
    int tx = dir ? (mylen - 1 - sc) : sc;
    const float* g = xwb + (size_t)tx * 2048;
    float g0 = g[hc], g1 = g[256 + hc], g2 = g[512 + hc], g3 = g[768 + hc];

    float a0 = 0.f, a1 = 0.f, a2 = 0.f, a3 = 0.f;

    // register slices 8..15
    DOT1(wr0,  8); DOT1(wr1,  9); DOT1(wr2, 10); DOT1(wr3, 11);
    DOT1(wr4, 12); DOT1(wr5, 13); DOT1(wr6, 14); DOT1(wr7, 15);

    // LDS slices 0..7 (conflict-free: consecutive lanes 16B apart)
    #pragma unroll
    for (int i = 0; i < NLDS; ++i) {
      uint4 wl = Wl[i * 1024 + tid];
      DOT1(wl, i);
    }

    // stream bank 2 (slices 24..31): issue before consuming bank 1
    uint4 sb0 = WHd[24 * 1024 + tid], sb1 = WHd[25 * 1024 + tid];
    uint4 sb2 = WHd[26 * 1024 + tid], sb3 = WHd[27 * 1024 + tid];
    uint4 sb4 = WHd[28 * 1024 + tid], sb5 = WHd[29 * 1024 + tid];
    uint4 sb6 = WHd[30 * 1024 + tid], sb7 = WHd[31 * 1024 + tid];

    DOT1(sa0, 16); DOT1(sa1, 17); DOT1(sa2, 18); DOT1(sa3, 19);
    DOT1(sa4, 20); DOT1(sa5, 21); DOT1(sa6, 22); DOT1(sa7, 23);
    DOT1(sb0, 24); DOT1(sb1, 25); DOT1(sb2, 26); DOT1(sb3, 27);
    DOT1(sb4, 28); DOT1(sb5, 29); DOT1(sb6, 30); DOT1(sb7, 31);

    // gacc[j][gate][hc]; tid = gate*256+hc
    gacc[0 * 1024 + tid] = a0;
    gacc[1 * 1024 + tid] = a1;
    gacc[2 * 1024 + tid] = a2;
    gacc[3 * 1024 + tid] = a3;
    __syncthreads();

    // update phase: thread = (batch j=hi, hidden hc); wave-uniform branch
    if (s < mylen) {
      float gi = g0 + gacc[hi * 1024 + 0   + hc];
      float gf = g1 + gacc[hi * 1024 + 256 + hc];
      float gg = g2 + gacc[hi * 1024 + 512 + hc];
      float go = g3 + gacc[hi * 1024 + 768 + hc];
      float si = 1.f / (1.f + expf(-gi));
      float sf = 1.f / (1.f + expf(-gf));
      float so = 1.f / (1.f + expf(-go));
      float cn = sf * cstate + si * tanhf(gg);
      float hn = so * tanhf(cn);
      cstate = cn;
      cbase[(size_t)tx * 512 + hc] = hn;
      hsT[(hc >> 1) * 8 + hi * 2 + (hc & 1)] = (_Float16)hn;
    }
    __syncthreads();
  }
  for (int t = mylen; t < T_; ++t) cbase[(size_t)t * 512 + hc] = 0.f;
}

// ---------------------------------------------------------------------------
// Per-b: avg over masked t, then tri[b][t][0..1] = (ctx+avg).W_tri^T + b_tri
// ---------------------------------------------------------------------------
__global__ __launch_bounds__(256) void k_avgtri(
    const float* __restrict__ ctx, const int* __restrict__ masks,
    const float* __restrict__ Wtri, const float* __restrict__ btri,
    float* __restrict__ tri) {
  int b = blockIdx.x, tid = threadIdx.x;
  __shared__ float av[512];
  __shared__ float wt[1024];
  wt[tid] = Wtri[tid];             wt[tid + 256] = Wtri[tid + 256];
  wt[tid + 512] = Wtri[tid + 512]; wt[tid + 768] = Wtri[tid + 768];
  const float* cb = ctx + (size_t)b * T_ * 512;
  float s0 = 0.f, s1 = 0.f, msum = 0.f;
  for (int t = 0; t < T_; ++t) {
    int m = masks[b * T_ + t];
    if (m) {
      float mf = (float)m;
      s0 += mf * cb[(size_t)t * 512 + tid];
      s1 += mf * cb[(size_t)t * 512 + 256 + tid];
      msum += mf;
    }
  }
  av[tid] = s0 / msum;
  av[256 + tid] = s1 / msum;
  __syncthreads();
  int wave = tid >> 6, lane = tid & 63;
  float bt0 = btri[0], bt1 = btri[1];
  for (int t = wave; t < T_; t += 4) {
    const float* cr = cb + (size_t)t * 512;
    float p0 = 0.f, p1 = 0.f;
    #pragma unroll
    for (int q = 0; q < 8; ++q) {
      int h = lane + q * 64;
      float x = cr[h] + av[h];
      p0 += x * wt[h];
      p1 += x * wt[512 + h];
    }
    #pragma unroll
    for (int off = 32; off > 0; off >>= 1) {
      p0 += __shfl_down(p0, off);
      p1 += __shfl_down(p1, off);
    }
    if (lane == 0) {
      tri[((size_t)b * T_ + t) * 2 + 0] = p0 + bt0;
      tri[((size_t)b * T_ + t) * 2 + 1] = p1 + bt1;
    }
  }
}

// ---------------------------------------------------------------------------
__device__ __forceinline__ float lse2(float a, float b) {
  float m = fmaxf(a, b);
  return m + logf(expf(a - m) + expf(b - m));
}

__global__ __launch_bounds__(64) void k_crf(
    const float* __restrict__ tri, const int* __restrict__ lens,
    const float* __restrict__ trans, float* __restrict__ alph,
    float* __restrict__ sel, float* __restrict__ snb) {
  int b = threadIdx.x;
  if (b >= 64) return;
  const float* f = tri + (size_t)b * T_ * 2;
  float* aw = alph + (size_t)b * T_ * 2;
  int L = lens[b];
  float t00 = trans[0], t01 = trans[1], t10 = trans[2], t11 = trans[3];
  float a0 = f[0], a1 = f[1];
  aw[0] = a0; aw[1] = a1;
  for (int t = 1; t < T_; ++t) {
    if (t < L) {
      float c0 = f[2 * t]     + lse2(a0 + t00, a1 + t01);
      float c1 = f[2 * t + 1] + lse2(a0 + t10, a1 + t11);
      a0 = c0; a1 = c1;
    }
    aw[2 * t] = a0; aw[2 * t + 1] = a1;
  }
  float logZ = lse2(aw[2 * (L - 1)], aw[2 * (L - 1) + 1]);
  float b0 = 0.f, b1 = 0.f, sn = 0.f;
  {
    float s = (T_ - 1 < L) ? expf(aw[2 * (T_ - 1) + 1] - logZ) : 0.f;
    sel[b * T_ + T_ - 1] = s; sn += s;
  }
  for (int t = T_ - 2; t >= 0; --t) {
    if (t < L - 1) {
      float e0 = b0 + f[2 * (t + 1)];
      float e1 = b1 + f[2 * (t + 1) + 1];
      float n0 = lse2(e0 + t00, e1 + t10);
      float n1 = lse2(e0 + t01, e1 + t11);
      b0 = n0; b1 = n1;
    } else { b0 = 0.f; b1 = 0.f; }
    float s = (t < L) ? expf(aw[2 * t + 1] + b1 - logZ) : 0.f;
    sel[b * T_ + t] = s; sn += s;
  }
  snb[b] = sn;
}

// ---------------------------------------------------------------------------
__global__ __launch_bounds__(256) void k_sentv(
    const float* __restrict__ ctx, const float* __restrict__ sel,
    const float* __restrict__ Wlab, const float* __restrict__ blab,
    float* __restrict__ scores) {
  int b = blockIdx.x, tid = threadIdx.x;
  __shared__ float ss[T_];
  __shared__ float red[3][4];
  ss[tid] = sel[b * T_ + tid];
  __syncthreads();
  const float* cb = ctx + (size_t)b * T_ * 512;
  float sv0 = 0.f, sv1 = 0.f;
  for (int t = 0; t < T_; ++t) {
    float s = ss[t];
    if (s != 0.f) {
      sv0 += s * cb[(size_t)t * 512 + tid];
      sv1 += s * cb[(size_t)t * 512 + 256 + tid];
    }
  }
  int wave = tid >> 6, lane = tid & 63;
  #pragma unroll
  for (int k = 0; k < 3; ++k) {
    float p = sv0 * Wlab[k * 512 + tid] + sv1 * Wlab[k * 512 + 256 + tid];
    #pragma unroll
    for (int off = 32; off > 0; off >>= 1) p += __shfl_down(p, off);
    if (lane == 0) red[k][wave] = p;
  }
  __syncthreads();
  if (tid < 3) {
    float r = red[tid][0] + red[tid][1] + red[tid][2] + red[tid][3];
    scores[b * 3 + tid] = r + blab[tid];
  }
}

// ---------------------------------------------------------------------------
__global__ __launch_bounds__(64) void k_final(
    const float* __restrict__ scores, const int* __restrict__ labels,
    const float* __restrict__ snb, const float* __restrict__ trans,
    float* __restrict__ out) {
  int b = threadIdx.x;
  float s0 = scores[b * 3], s1 = scores[b * 3 + 1], s2 = scores[b * 3 + 2];
  float m = fmaxf(s0, fmaxf(s1, s2));
  float lse = m + logf(expf(s0 - m) + expf(s1 - m) + expf(s2 - m));
  int lab = labels[b];
  float sl = lab == 0 ? s0 : (lab == 1 ? s1 : s2);
  float closs = lse - sl;
  float sn = snb[b];
  #pragma unroll
  for (int off = 32; off > 0; off >>= 1) {
    closs += __shfl_down(closs, off);
    sn    += __shfl_down(sn, off);
  }
  if (b == 0) {
    float pena = fmaxf(trans[2] - trans[0], 0.f) + fmaxf(trans[1] - trans[3], 0.f);
    out[0] = closs / 64.f;
    out[1] = pena / 64.f + sn / 64.f;
  }
}

// ---------------------------------------------------------------------------
extern "C" void kernel_launch(void* const* d_in, const int* in_sizes, int n_in,
                              void* d_out, int out_size, void* d_ws, size_t ws_size,
                              hipStream_t stream) {
  const float* sents  = (const float*)d_in[0];
  const int*   masks  = (const int*)d_in[1];
  const int*   lens   = (const int*)d_in[2];
  const int*   labels = (const int*)d_in[3];
  const float* me     = (const float*)d_in[4];
  const float* Wihf   = (const float*)d_in[5];
  const float* Whhf   = (const float*)d_in[6];
  const float* bf     = (const float*)d_in[7];
  const float* Wihb   = (const float*)d_in[8];
  const float* Whhb   = (const float*)d_in[9];
  const float* bb     = (const float*)d_in[10];
  const float* Wtri   = (const float*)d_in[11];
  const float* btri   = (const float*)d_in[12];
  const float* Wlab   = (const float*)d_in[13];
  const float* blab   = (const float*)d_in[14];
  const float* trans  = (const float*)d_in[15];
  float* out = (float*)d_out;

  float*     XW   = (float*)d_ws;                              // 16384*2048 f (128MiB)
  float*     CTX  = XW + (size_t)16384 * 2048;                 // 8388608 f (32MiB)
  _Float16*  PA   = (_Float16*)CTX;                            // overlaps CTX (dead until k_lstm)
  _Float16*  WH   = (_Float16*)(CTX + (size_t)64 * 256 * 512); // 524288 halfs (1MiB)
  float*     PRE  = (float*)(WH + 524288);                     // 4096
  float*     TRI  = PRE + 4096;                                // 32768
  float*     ALPH = TRI + 32768;                               // 32768
  float*     SEL  = ALPH + 32768;                              // 16384
  float*     SCOR = SEL + 16384;                               // 192
  float*     SNB  = SCOR + 192;                                // 64
  _Float16*  PB   = (_Float16*)(SNB + 64);                     // 2097152 halfs (4MiB)

  hipLaunchKernelGGL(k_pre,    dim3(16),       dim3(256),  0, stream, me, Wihf, Wihb, bf, bb, PRE);
  hipLaunchKernelGGL(k_wph,    dim3(256),      dim3(256),  0, stream, Whhf, Whhb, WH);
  hipLaunchKernelGGL(k_pack,   dim3(9216),     dim3(256),  0, stream, sents, Wihf, Wihb, PA, PB);
  hipLaunchKernelGGL(k_mm,     dim3(16, 128),  dim3(256),  0, stream, PA, PB, PRE, masks, XW);
  hipLaunchKernelGGL(k_lstm,   dim3(32),       dim3(1024), 0, stream, XW, WH, lens, CTX);
  hipLaunchKernelGGL(k_avgtri, dim3(64),       dim3(256),  0, stream, CTX, masks, Wtri, btri, TRI);
  hipLaunchKernelGGL(k_crf,    dim3(1),        dim3(64),   0, stream, TRI, lens, trans, ALPH, SEL, SNB);
  hipLaunchKernelGGL(k_sentv,  dim3(64),       dim3(256),  0, stream, CTX, SEL, Wlab, blab, SCOR);
  hipLaunchKernelGGL(k_final,  dim3(1),        dim3(64),   0, stream, SCOR, labels, SNB, trans, out);
}

// Round 8
// 1148.576 us; speedup vs baseline: 2.1429x; 2.1429x over previous
//
#include <hip/hip_runtime.h>
#include <cmath>

#define B_   64
#define T_   256
#define D_   1024
#define DIN_ 1074
#define H_   256

typedef _Float16 h2_t  __attribute__((ext_vector_type(2)));
typedef _Float16 f16x8 __attribute__((ext_vector_type(8)));
typedef float    f32x4 __attribute__((ext_vector_type(4)));

// ---------------------------------------------------------------------------
// PRE[mv][n] = bias_dir[row] + sum_{k<50} mask_embed[mv][k] * W_ih_dir[row][1024+k]
// ---------------------------------------------------------------------------
__global__ __launch_bounds__(256) void k_pre(
    const float* __restrict__ me, const float* __restrict__ Wf,
    const float* __restrict__ Wb, const float* __restrict__ bf,
    const float* __restrict__ bb, float* __restrict__ PRE) {
  int idx = blockIdx.x * 256 + threadIdx.x;   // 4096 total
  if (idx >= 4096) return;
  int mv = idx >> 11, n = idx & 2047;
  int dir = n >> 10, row = n & 1023;
  const float* W    = dir ? Wb : Wf;
  const float* bias = dir ? bb : bf;
  const float* wrow = W + (size_t)row * DIN_ + 1024;
  const float* m    = me + mv * 50;
  float s = bias[row];
  #pragma unroll 10
  for (int k = 0; k < 50; ++k) s += m[k] * wrow[k];
  PRE[idx] = s;
}

// ---------------------------------------------------------------------------
// Pack W_hh (both dirs) to fp16, layout WH[dir][k8][row=gate*256+hc][8 halfs]
// ---------------------------------------------------------------------------
__global__ __launch_bounds__(256) void k_wph(
    const float* __restrict__ Whf, const float* __restrict__ Whb,
    _Float16* __restrict__ WH) {
  int idx = blockIdx.x * 256 + threadIdx.x;   // 65536 total
  int dir = idx >> 15, rem = idx & 32767;
  int k8 = rem >> 10, gate = (rem >> 8) & 3, hc = rem & 255;
  const float* W = dir ? Whb : Whf;
  const float* src = W + (size_t)(gate * 256 + hc) * H_ + k8 * 8;
  _Float16* dst = WH + ((size_t)(((dir * 32 + k8) * 4 + gate) * 256 + hc)) * 8;
  #pragma unroll
  for (int e = 0; e < 8; ++e) dst[e] = (_Float16)src[e];
}

// ---------------------------------------------------------------------------
// Pack sents -> PA fp16 [16384][1024] and W_ih rows (cols 0..1023) -> PB fp16
// ---------------------------------------------------------------------------
__global__ __launch_bounds__(256) void k_pack(
    const float* __restrict__ sents, const float* __restrict__ Wf,
    const float* __restrict__ Wb, _Float16* __restrict__ PA,
    _Float16* __restrict__ PB) {
  int i = blockIdx.x * 256 + threadIdx.x;     // 2359296 total
  if (i < 2097152) {
    size_t off = (size_t)i * 8;
    float4 a = *(const float4*)(sents + off);
    float4 b = *(const float4*)(sents + off + 4);
    _Float16 h[8] = {(_Float16)a.x, (_Float16)a.y, (_Float16)a.z, (_Float16)a.w,
                     (_Float16)b.x, (_Float16)b.y, (_Float16)b.z, (_Float16)b.w};
    *(uint4*)(PA + off) = *(const uint4*)h;
  } else {
    int j = i - 2097152;                      // 262144
    int n = j >> 7, k8 = j & 127;
    const float* src = (n < 1024) ? (Wf + (size_t)n * DIN_ + k8 * 8)
                                  : (Wb + (size_t)(n - 1024) * DIN_ + k8 * 8);
    float2 a0 = *(const float2*)(src);
    float2 a1 = *(const float2*)(src + 2);
    float2 a2 = *(const float2*)(src + 4);
    float2 a3 = *(const float2*)(src + 6);
    _Float16 h[8] = {(_Float16)a0.x, (_Float16)a0.y, (_Float16)a1.x, (_Float16)a1.y,
                     (_Float16)a2.x, (_Float16)a2.y, (_Float16)a3.x, (_Float16)a3.y};
    *(uint4*)(PB + (size_t)n * 1024 + k8 * 8) = *(const uint4*)h;
  }
}

// ---------------------------------------------------------------------------
// XW = PA @ PB^T + PRE[mask] : M=16384, N=2048, K=1024, fp16 MFMA 16x16x32.
// LDS row stride 40 halfs (80B): fragment reads are 2-way bank aliased (free).
// ---------------------------------------------------------------------------
#define LSTR 40
__global__ __launch_bounds__(256) void k_mm(
    const _Float16* __restrict__ PA, const _Float16* __restrict__ PB,
    const float* __restrict__ PRE, const int* __restrict__ masks,
    float* __restrict__ XW) {
  __shared__ __align__(16) _Float16 Al[128 * LSTR];
  __shared__ __align__(16) _Float16 Bl[128 * LSTR];
  int tid = threadIdx.x;
  int lane = tid & 63, wave = tid >> 6;
  int wr = wave >> 1, wc = wave & 1;
  int m0 = blockIdx.y * 128, n0 = blockIdx.x * 128;

  int r0 = tid >> 2;
  int kc = (tid & 3) * 8;
  const _Float16* asrc0 = PA + (size_t)(m0 + r0) * 1024 + kc;
  const _Float16* asrc1 = asrc0 + (size_t)64 * 1024;
  const _Float16* bsrc0 = PB + (size_t)(n0 + r0) * 1024 + kc;
  const _Float16* bsrc1 = bsrc0 + (size_t)64 * 1024;
  _Float16* adst0 = Al + r0 * LSTR + kc;
  _Float16* adst1 = Al + (r0 + 64) * LSTR + kc;
  _Float16* bdst0 = Bl + r0 * LSTR + kc;
  _Float16* bdst1 = Bl + (r0 + 64) * LSTR + kc;

  f32x4 acc[4][4];
  #pragma unroll
  for (int i = 0; i < 4; ++i)
    #pragma unroll
    for (int j = 0; j < 4; ++j)
      acc[i][j] = (f32x4){0.f, 0.f, 0.f, 0.f};

  int fr = lane & 15, fk = (lane >> 4) * 8;
  const _Float16* arow = Al + (wr * 64 + fr) * LSTR + fk;
  const _Float16* brow = Bl + (wc * 64 + fr) * LSTR + fk;

  for (int k0 = 0; k0 < 1024; k0 += 32) {
    uint4 a0 = *(const uint4*)(asrc0 + k0);
    uint4 a1 = *(const uint4*)(asrc1 + k0);
    uint4 b0 = *(const uint4*)(bsrc0 + k0);
    uint4 b1 = *(const uint4*)(bsrc1 + k0);
    __syncthreads();
    *(uint4*)adst0 = a0; *(uint4*)adst1 = a1;
    *(uint4*)bdst0 = b0; *(uint4*)bdst1 = b1;
    __syncthreads();
    f16x8 af[4], bf[4];
    #pragma unroll
    for (int fm = 0; fm < 4; ++fm) af[fm] = *(const f16x8*)(arow + fm * 16 * LSTR);
    #pragma unroll
    for (int fn = 0; fn < 4; ++fn) bf[fn] = *(const f16x8*)(brow + fn * 16 * LSTR);
    #pragma unroll
    for (int fm = 0; fm < 4; ++fm)
      #pragma unroll
      for (int fn = 0; fn < 4; ++fn)
        acc[fm][fn] = __builtin_amdgcn_mfma_f32_16x16x32_f16(af[fm], bf[fn], acc[fm][fn], 0, 0, 0);
  }

  int cr = (lane >> 4) * 4;
  #pragma unroll
  for (int fm = 0; fm < 4; ++fm) {
    #pragma unroll
    for (int r = 0; r < 4; ++r) {
      int m = m0 + wr * 64 + fm * 16 + cr + r;
      int mv = masks[m];
      const float* pr = PRE + mv * 2048;
      float* orow = XW + (size_t)m * 2048;
      #pragma unroll
      for (int fn = 0; fn < 4; ++fn) {
        int n = n0 + wc * 64 + fn * 16 + fr;
        orow[n] = acc[fm][fn][r] + pr[n];
      }
    }
  }
}

// ---------------------------------------------------------------------------
// Persistent LSTM v8: 1 chain per WG -> 128 WGs x 1024 thr (128 CUs active).
// Thread owns ONE gate-row (row = tid) for ONE chain: per step only
//   32 broadcast hp-reads (vs 128 in r2-r7 -- the invariant LDS-issue wall),
//   128 fdot2, 256KB W-stream (8 LDS-resident + 8 reg + 16 streamed slices).
// XW value for the row folds into gacc before the barrier (no update-phase
// global read). Steps run to this chain's own len (no group max).
// VGPR demand ~115 -- inside the allocator's 128 budget by construction.
// ---------------------------------------------------------------------------
#define DOT1(W, K8)                                                     \
  {                                                                     \
    const unsigned int* wq_ = (const unsigned int*)&(W);                \
    uint4 hv_ = hp[(K8)];                                               \
    const unsigned int* hq_ = (const unsigned int*)&hv_;                \
    _Pragma("unroll")                                                   \
    for (int q_ = 0; q_ < 4; ++q_) {                                    \
      a0 = __builtin_amdgcn_fdot2(__builtin_bit_cast(h2_t, wq_[q_]),    \
                                  __builtin_bit_cast(h2_t, hq_[q_]),    \
                                  a0, false);                           \
    }                                                                   \
  }

__global__ __launch_bounds__(1024) void k_lstm(
    const float* __restrict__ XW, const _Float16* __restrict__ WH,
    const int* __restrict__ lens, float* __restrict__ ctx) {
  int bx = blockIdx.x;
  int dir = bx & 1, b = bx >> 1;
  int tid = threadIdx.x;
  int hc = tid & 255;

  __shared__ __align__(16) uint4    Wl[8 * 1024];   // 128 KB
  __shared__ __align__(16) _Float16 hs[256];        // 512 B, linear h[k]
  __shared__ __align__(16) float    gacc[1024];     // 4 KB  [gate*256+hc]

  int len = lens[b];
  const uint4* WHd = (const uint4*)WH + (size_t)dir * 32768;

  // one-time LDS preload of slices 0..7 (coalesced)
  #pragma unroll
  for (int i = 0; i < 8; ++i) Wl[i * 1024 + tid] = WHd[i * 1024 + tid];

  // register-resident slices 8..15 (32 VGPRs)
  uint4 wr0 = WHd[ 8 * 1024 + tid];
  uint4 wr1 = WHd[ 9 * 1024 + tid];
  uint4 wr2 = WHd[10 * 1024 + tid];
  uint4 wr3 = WHd[11 * 1024 + tid];
  uint4 wr4 = WHd[12 * 1024 + tid];
  uint4 wr5 = WHd[13 * 1024 + tid];
  uint4 wr6 = WHd[14 * 1024 + tid];
  uint4 wr7 = WHd[15 * 1024 + tid];

  if (tid < 256) hs[tid] = (_Float16)0.f;
  float cstate = 0.f;

  const uint4* hp = (const uint4*)hs;
  const float* xwb = XW + (size_t)b * T_ * 2048 + dir * 1024;
  float* cbase = ctx + (size_t)b * T_ * 512 + dir * 256;
  __syncthreads();

  for (int s = 0; s < len; ++s) {
    // stream bank 1 (slices 16..23): issue first, consume after reg+LDS dots
    uint4 sa0 = WHd[16 * 1024 + tid], sa1 = WHd[17 * 1024 + tid];
    uint4 sa2 = WHd[18 * 1024 + tid], sa3 = WHd[19 * 1024 + tid];
    uint4 sa4 = WHd[20 * 1024 + tid], sa5 = WHd[21 * 1024 + tid];
    uint4 sa6 = WHd[22 * 1024 + tid], sa7 = WHd[23 * 1024 + tid];

    // this row's XW gate value (coalesced 4KB per WG)
    int tx = dir ? (len - 1 - s) : s;
    float gown = xwb[(size_t)tx * 2048 + tid];

    float a0 = 0.f;

    // register slices 8..15
    DOT1(wr0,  8); DOT1(wr1,  9); DOT1(wr2, 10); DOT1(wr3, 11);
    DOT1(wr4, 12); DOT1(wr5, 13); DOT1(wr6, 14); DOT1(wr7, 15);

    // LDS slices 0..7
    #pragma unroll
    for (int i = 0; i < 8; ++i) {
      uint4 wl = Wl[i * 1024 + tid];
      DOT1(wl, i);
    }

    // stream bank 2 (slices 24..31): issue before consuming bank 1
    uint4 sb0 = WHd[24 * 1024 + tid], sb1 = WHd[25 * 1024 + tid];
    uint4 sb2 = WHd[26 * 1024 + tid], sb3 = WHd[27 * 1024 + tid];
    uint4 sb4 = WHd[28 * 1024 + tid], sb5 = WHd[29 * 1024 + tid];
    uint4 sb6 = WHd[30 * 1024 + tid], sb7 = WHd[31 * 1024 + tid];

    DOT1(sa0, 16); DOT1(sa1, 17); DOT1(sa2, 18); DOT1(sa3, 19);
    DOT1(sa4, 20); DOT1(sa5, 21); DOT1(sa6, 22); DOT1(sa7, 23);
    DOT1(sb0, 24); DOT1(sb1, 25); DOT1(sb2, 26); DOT1(sb3, 27);
    DOT1(sb4, 28); DOT1(sb5, 29); DOT1(sb6, 30); DOT1(sb7, 31);

    gacc[tid] = a0 + gown;
    __syncthreads();

    // update: waves 0..3 only (wave-uniform branch), thread = hidden unit hc
    if (tid < 256) {
      float gi = gacc[hc];
      float gf = gacc[256 + hc];
      float gg = gacc[512 + hc];
      float go = gacc[768 + hc];
      float si = 1.f / (1.f + expf(-gi));
      float sf = 1.f / (1.f + expf(-gf));
      float so = 1.f / (1.f + expf(-go));
      float cn = sf * cstate + si * tanhf(gg);
      float hn = so * tanhf(cn);
      cstate = cn;
      cbase[(size_t)tx * 512 + hc] = hn;
      hs[hc] = (_Float16)hn;
    }
    __syncthreads();
  }
  // tail zero-fill, 4 waves-groups handle interleaved t
  for (int t = len + (tid >> 8); t < T_; t += 4)
    cbase[(size_t)t * 512 + hc] = 0.f;
}

// ---------------------------------------------------------------------------
// Per-b: avg over masked t, then tri[b][t][0..1] = (ctx+avg).W_tri^T + b_tri
// ---------------------------------------------------------------------------
__global__ __launch_bounds__(256) void k_avgtri(
    const float* __restrict__ ctx, const int* __restrict__ masks,
    const float* __restrict__ Wtri, const float* __restrict__ btri,
    float* __restrict__ tri) {
  int b = blockIdx.x, tid = threadIdx.x;
  __shared__ float av[512];
  __shared__ float wt[1024];
  wt[tid] = Wtri[tid];             wt[tid + 256] = Wtri[tid + 256];
  wt[tid + 512] = Wtri[tid + 512]; wt[tid + 768] = Wtri[tid + 768];
  const float* cb = ctx + (size_t)b * T_ * 512;
  float s0 = 0.f, s1 = 0.f, msum = 0.f;
  for (int t = 0; t < T_; ++t) {
    int m = masks[b * T_ + t];
    if (m) {
      float mf = (float)m;
      s0 += mf * cb[(size_t)t * 512 + tid];
      s1 += mf * cb[(size_t)t * 512 + 256 + tid];
      msum += mf;
    }
  }
  av[tid] = s0 / msum;
  av[256 + tid] = s1 / msum;
  __syncthreads();
  int wave = tid >> 6, lane = tid & 63;
  float bt0 = btri[0], bt1 = btri[1];
  for (int t = wave; t < T_; t += 4) {
    const float* cr = cb + (size_t)t * 512;
    float p0 = 0.f, p1 = 0.f;
    #pragma unroll
    for (int q = 0; q < 8; ++q) {
      int h = lane + q * 64;
      float x = cr[h] + av[h];
      p0 += x * wt[h];
      p1 += x * wt[512 + h];
    }
    #pragma unroll
    for (int off = 32; off > 0; off >>= 1) {
      p0 += __shfl_down(p0, off);
      p1 += __shfl_down(p1, off);
    }
    if (lane == 0) {
      tri[((size_t)b * T_ + t) * 2 + 0] = p0 + bt0;
      tri[((size_t)b * T_ + t) * 2 + 1] = p1 + bt1;
    }
  }
}

// ---------------------------------------------------------------------------
__device__ __forceinline__ float lse2(float a, float b) {
  float m = fmaxf(a, b);
  return m + logf(expf(a - m) + expf(b - m));
}

__global__ __launch_bounds__(64) void k_crf(
    const float* __restrict__ tri, const int* __restrict__ lens,
    const float* __restrict__ trans, float* __restrict__ alph,
    float* __restrict__ sel, float* __restrict__ snb) {
  int b = threadIdx.x;
  if (b >= 64) return;
  const float* f = tri + (size_t)b * T_ * 2;
  float* aw = alph + (size_t)b * T_ * 2;
  int L = lens[b];
  float t00 = trans[0], t01 = trans[1], t10 = trans[2], t11 = trans[3];
  float a0 = f[0], a1 = f[1];
  aw[0] = a0; aw[1] = a1;
  for (int t = 1; t < T_; ++t) {
    if (t < L) {
      float c0 = f[2 * t]     + lse2(a0 + t00, a1 + t01);
      float c1 = f[2 * t + 1] + lse2(a0 + t10, a1 + t11);
      a0 = c0; a1 = c1;
    }
    aw[2 * t] = a0; aw[2 * t + 1] = a1;
  }
  float logZ = lse2(aw[2 * (L - 1)], aw[2 * (L - 1) + 1]);
  float b0 = 0.f, b1 = 0.f, sn = 0.f;
  {
    float s = (T_ - 1 < L) ? expf(aw[2 * (T_ - 1) + 1] - logZ) : 0.f;
    sel[b * T_ + T_ - 1] = s; sn += s;
  }
  for (int t = T_ - 2; t >= 0; --t) {
    if (t < L - 1) {
      float e0 = b0 + f[2 * (t + 1)];
      float e1 = b1 + f[2 * (t + 1) + 1];
      float n0 = lse2(e0 + t00, e1 + t10);
      float n1 = lse2(e0 + t01, e1 + t11);
      b0 = n0; b1 = n1;
    } else { b0 = 0.f; b1 = 0.f; }
    float s = (t < L) ? expf(aw[2 * t + 1] + b1 - logZ) : 0.f;
    sel[b * T_ + t] = s; sn += s;
  }
  snb[b] = sn;
}

// ---------------------------------------------------------------------------
__global__ __launch_bounds__(256) void k_sentv(
    const float* __restrict__ ctx, const float* __restrict__ sel,
    const float* __restrict__ Wlab, const float* __restrict__ blab,
    float* __restrict__ scores) {
  int b = blockIdx.x, tid = threadIdx.x;
  __shared__ float ss[T_];
  __shared__ float red[3][4];
  ss[tid] = sel[b * T_ + tid];
  __syncthreads();
  const float* cb = ctx + (size_t)b * T_ * 512;
  float sv0 = 0.f, sv1 = 0.f;
  for (int t = 0; t < T_; ++t) {
    float s = ss[t];
    if (s != 0.f) {
      sv0 += s * cb[(size_t)t * 512 + tid];
      sv1 += s * cb[(size_t)t * 512 + 256 + tid];
    }
  }
  int wave = tid >> 6, lane = tid & 63;
  #pragma unroll
  for (int k = 0; k < 3; ++k) {
    float p = sv0 * Wlab[k * 512 + tid] + sv1 * Wlab[k * 512 + 256 + tid];
    #pragma unroll
    for (int off = 32; off > 0; off >>= 1) p += __shfl_down(p, off);
    if (lane == 0) red[k][wave] = p;
  }
  __syncthreads();
  if (tid < 3) {
    float r = red[tid][0] + red[tid][1] + red[tid][2] + red[tid][3];
    scores[b * 3 + tid] = r + blab[tid];
  }
}

// ---------------------------------------------------------------------------
__global__ __launch_bounds__(64) void k_final(
    const float* __restrict__ scores, const int* __restrict__ labels,
    const float* __restrict__ snb, const float* __restrict__ trans,
    float* __restrict__ out) {
  int b = threadIdx.x;
  float s0 = scores[b * 3], s1 = scores[b * 3 + 1], s2 = scores[b * 3 + 2];
  float m = fmaxf(s0, fmaxf(s1, s2));
  float lse = m + logf(expf(s0 - m) + expf(s1 - m) + expf(s2 - m));
  int lab = labels[b];
  float sl = lab == 0 ? s0 : (lab == 1 ? s1 : s2);
  float closs = lse - sl;
  float sn = snb[b];
  #pragma unroll
  for (int off = 32; off > 0; off >>= 1) {
    closs += __shfl_down(closs, off);
    sn    += __shfl_down(sn, off);
  }
  if (b == 0) {
    float pena = fmaxf(trans[2] - trans[0], 0.f) + fmaxf(trans[1] - trans[3], 0.f);
    out[0] = closs / 64.f;
    out[1] = pena / 64.f + sn / 64.f;
  }
}

// ---------------------------------------------------------------------------
extern "C" void kernel_launch(void* const* d_in, const int* in_sizes, int n_in,
                              void* d_out, int out_size, void* d_ws, size_t ws_size,
                              hipStream_t stream) {
  const float* sents  = (const float*)d_in[0];
  const int*   masks  = (const int*)d_in[1];
  const int*   lens   = (const int*)d_in[2];
  const int*   labels = (const int*)d_in[3];
  const float* me     = (const float*)d_in[4];
  const float* Wihf   = (const float*)d_in[5];
  const float* Whhf   = (const float*)d_in[6];
  const float* bf     = (const float*)d_in[7];
  const float* Wihb   = (const float*)d_in[8];
  const float* Whhb   = (const float*)d_in[9];
  const float* bb     = (const float*)d_in[10];
  const float* Wtri   = (const float*)d_in[11];
  const float* btri   = (const float*)d_in[12];
  const float* Wlab   = (const float*)d_in[13];
  const float* blab   = (const float*)d_in[14];
  const float* trans  = (const float*)d_in[15];
  float* out = (float*)d_out;

  float*     XW   = (float*)d_ws;                              // 16384*2048 f (128MiB)
  float*     CTX  = XW + (size_t)16384 * 2048;                 // 8388608 f (32MiB)
  _Float16*  PA   = (_Float16*)CTX;                            // overlaps CTX (dead until k_lstm)
  _Float16*  WH   = (_Float16*)(CTX + (size_t)64 * 256 * 512); // 524288 halfs (1MiB)
  float*     PRE  = (float*)(WH + 524288);                     // 4096
  float*     TRI  = PRE + 4096;                                // 32768
  float*     ALPH = TRI + 32768;                               // 32768
  float*     SEL  = ALPH + 32768;                              // 16384
  float*     SCOR = SEL + 16384;                               // 192
  float*     SNB  = SCOR + 192;                                // 64
  _Float16*  PB   = (_Float16*)(SNB + 64);                     // 2097152 halfs (4MiB)

  hipLaunchKernelGGL(k_pre,    dim3(16),       dim3(256),  0, stream, me, Wihf, Wihb, bf, bb, PRE);
  hipLaunchKernelGGL(k_wph,    dim3(256),      dim3(256),  0, stream, Whhf, Whhb, WH);
  hipLaunchKernelGGL(k_pack,   dim3(9216),     dim3(256),  0, stream, sents, Wihf, Wihb, PA, PB);
  hipLaunchKernelGGL(k_mm,     dim3(16, 128),  dim3(256),  0, stream, PA, PB, PRE, masks, XW);
  hipLaunchKernelGGL(k_lstm,   dim3(128),      dim3(1024), 0, stream, XW, WH, lens, CTX);
  hipLaunchKernelGGL(k_avgtri, dim3(64),       dim3(256),  0, stream, CTX, masks, Wtri, btri, TRI);
  hipLaunchKernelGGL(k_crf,    dim3(1),        dim3(64),   0, stream, TRI, lens, trans, ALPH, SEL, SNB);
  hipLaunchKernelGGL(k_sentv,  dim3(64),       dim3(256),  0, stream, CTX, SEL, Wlab, blab, SCOR);
  hipLaunchKernelGGL(k_final,  dim3(1),        dim3(64),   0, stream, SCOR, labels, SNB, trans, out);
}